// Round 4
// baseline (2690.119 us; speedup 1.0000x reference)
//
#include <hip/hip_runtime.h>
#include <stdint.h>

#define NN 20000      // nodes
#define NE 320000     // edges
#define NBATCH 16

typedef short short8 __attribute__((ext_vector_type(8)));   // 8 x bf16 bits (4 VGPR)
typedef float f32x4  __attribute__((ext_vector_type(4)));   // MFMA acc

__device__ __forceinline__ unsigned short f2bf(float f) {
  union { float f; unsigned u; } v; v.f = f;
  unsigned r = v.u + 0x7FFFu + ((v.u >> 16) & 1u);   // RNE
  return (unsigned short)(r >> 16);
}
__device__ __forceinline__ float bf2f(unsigned short h) {
  union { unsigned u; float f; } v; v.u = ((unsigned)h) << 16;
  return v.f;
}
__device__ __forceinline__ float bf2fs(short h) { return bf2f((unsigned short)h); }

// LDS tile: 128 edges x 256 bf16, XOR-swizzled 16B granules, exactly 64 KB.
#define HOFF(e, k) (((e) << 8) + (((((k) >> 3) ^ ((e) & 7)) << 3) + ((k) & 7)))

// ---------------- weight prep: fp32 [K,N] -> bf16 transposed [N,K] (or plain cast) ----------------
struct TD { const float* s; unsigned short* d; int R, C, r0, ld; };
struct TDs { TD t[13]; };

__global__ void wprep(TDs all) {
  TD td = all.t[blockIdx.y];
  int stride = gridDim.x * blockDim.x;
  int i0 = blockIdx.x * blockDim.x + threadIdx.x;
  if (td.ld == 0) {                       // plain cast copy
    for (int i = i0; i < td.R; i += stride) td.d[i] = f2bf(td.s[i]);
  } else {                                // dst[c*R + r] = src[(r0+r)*ld + c]
    int total = td.R * td.C;
    for (int i = i0; i < total; i += stride) {
      int c = i / td.R;
      int r = i - c * td.R;
      td.d[i] = f2bf(td.s[(size_t)(td.r0 + r) * td.ld + c]);
    }
  }
}

// ---------------- generic transposed-weight GEMM: Out[r][f] = In[r][:] . WT[f][:] ----------------
// block tile: 256 out-features x 128 rows; 8 waves, each 64x64; frags direct from global (L2-hot).
template <int EPI>  // 0: bf16 store (+bias), 1: bf16 relu(+bias), 2: f32 store (+bias)
__global__ __launch_bounds__(512, 4) void gemmT(
    const unsigned short* __restrict__ WT, const unsigned short* __restrict__ In,
    const float* __restrict__ bias, void* __restrict__ Out,
    int M, int K, int Nout, int ldo) {
  const int tid = threadIdx.x;
  const int lane = tid & 63, w = tid >> 6;
  const int wf = w >> 1, we = w & 1;
  const int l15 = lane & 15, q = lane >> 4;
  const int fb = blockIdx.x * 256 + wf * 64;
  const int rb = blockIdx.y * 128 + we * 64;
  f32x4 acc[4][4] = {};
  const short8 zz = {0, 0, 0, 0, 0, 0, 0, 0};
  for (int kc = 0; kc < K; kc += 32) {
    short8 a[4], bq[4];
#pragma unroll
    for (int i = 0; i < 4; ++i) {
      if (fb + i * 16 < Nout)
        a[i] = *(const short8*)(WT + (size_t)(fb + i * 16 + l15) * K + kc + q * 8);
      else
        a[i] = zz;
      int r = rb + i * 16 + l15;
      if (r >= M) r = M - 1;  // clamp: stores guarded below
      bq[i] = *(const short8*)(In + (size_t)r * K + kc + q * 8);
    }
#pragma unroll
    for (int i = 0; i < 4; ++i)
#pragma unroll
      for (int j = 0; j < 4; ++j)
        acc[i][j] = __builtin_amdgcn_mfma_f32_16x16x32_bf16(a[i], bq[j], acc[i][j], 0, 0, 0);
  }
#pragma unroll
  for (int i = 0; i < 4; ++i) {
    int f0 = fb + i * 16 + q * 4;
    if (f0 >= Nout) continue;
    float4 bs = make_float4(0.f, 0.f, 0.f, 0.f);
    if (bias) bs = *(const float4*)(bias + f0);
#pragma unroll
    for (int j = 0; j < 4; ++j) {
      int r = rb + j * 16 + l15;
      if (r >= M) continue;
      float v0 = acc[i][j][0] + bs.x;
      float v1 = acc[i][j][1] + bs.y;
      float v2 = acc[i][j][2] + bs.z;
      float v3 = acc[i][j][3] + bs.w;
      if (EPI == 1) {
        v0 = fmaxf(v0, 0.f); v1 = fmaxf(v1, 0.f); v2 = fmaxf(v2, 0.f); v3 = fmaxf(v3, 0.f);
      }
      if (EPI == 2) {
        *(float4*)((float*)Out + (size_t)r * ldo + f0) = make_float4(v0, v1, v2, v3);
      } else {
        ushort4 o;
        o.x = f2bf(v0); o.y = f2bf(v1); o.z = f2bf(v2); o.w = f2bf(v3);
        *(ushort4*)((unsigned short*)Out + (size_t)r * ldo + f0) = o;
      }
    }
  }
}

// ---------------- fused per-edge MLP (one per GNN layer) ----------------
// h1 = relu(PQ[dst][0:256] + PQ[src][256:512] + b1)      (LDS, 128 edges)
// h2 = relu(h1 @ W2 + b2)                                 (LDS, overwrite)
// agg[dst] += h2 @ W3 + b3                                (fp32 atomics)
__global__ __launch_bounds__(512, 4) void edge_mlp(
    const unsigned short* __restrict__ PQ, const int* __restrict__ srcI,
    const int* __restrict__ dstI, const float* __restrict__ b1,
    const unsigned short* __restrict__ W2T, const float* __restrict__ b2,
    const unsigned short* __restrict__ W3T, const float* __restrict__ b3,
    float* __restrict__ agg) {
  __shared__ __align__(16) unsigned short h[128 * 256];  // 64 KB, swizzled
  const int tid = threadIdx.x;
  const int e0 = blockIdx.x * 128;

  {  // phase 0: gather + h1
    int r = tid >> 2;
    int c0 = (tid & 3) * 64;
    int dn = dstI[e0 + r];
    int sn = srcI[e0 + r];
    const unsigned short* pd = PQ + (size_t)dn * 512 + c0;
    const unsigned short* ps = PQ + (size_t)sn * 512 + 256 + c0;
    const float* bp = b1 + c0;
#pragma unroll
    for (int i = 0; i < 8; ++i) {
      short8 dv = *(const short8*)(pd + i * 8);
      short8 sv = *(const short8*)(ps + i * 8);
      float4 bA = *(const float4*)(bp + i * 8);
      float4 bB = *(const float4*)(bp + i * 8 + 4);
      float bb[8] = {bA.x, bA.y, bA.z, bA.w, bB.x, bB.y, bB.z, bB.w};
      short8 o;
#pragma unroll
      for (int j = 0; j < 8; ++j) {
        float v = bf2fs(dv[j]) + bf2fs(sv[j]) + bb[j];
        o[j] = (short)f2bf(fmaxf(v, 0.f));
      }
      *(short8*)&h[HOFF(r, c0 + i * 8)] = o;
    }
  }
  __syncthreads();

  const int lane = tid & 63, w = tid >> 6;
  const int wf = w >> 1, we = w & 1;
  const int l15 = lane & 15, q = lane >> 4;
  const int fb = wf * 64, eb = we * 64;
  f32x4 acc[4][4];

  // ---- GEMM1: h2^T = W2T @ h1^T ----
#pragma unroll
  for (int i = 0; i < 4; ++i)
#pragma unroll
    for (int j = 0; j < 4; ++j) { f32x4 z = {0.f, 0.f, 0.f, 0.f}; acc[i][j] = z; }
  for (int kc = 0; kc < 256; kc += 32) {
    short8 a[4], bq[4];
#pragma unroll
    for (int i = 0; i < 4; ++i)
      a[i] = *(const short8*)(W2T + (size_t)(fb + i * 16 + l15) * 256 + kc + q * 8);
#pragma unroll
    for (int j = 0; j < 4; ++j)
      bq[j] = *(const short8*)&h[HOFF(eb + j * 16 + l15, kc + q * 8)];
#pragma unroll
    for (int i = 0; i < 4; ++i)
#pragma unroll
      for (int j = 0; j < 4; ++j)
        acc[i][j] = __builtin_amdgcn_mfma_f32_16x16x32_bf16(a[i], bq[j], acc[i][j], 0, 0, 0);
  }
  __syncthreads();  // all reads of h1 done
#pragma unroll
  for (int i = 0; i < 4; ++i) {
    int f0 = fb + i * 16 + q * 4;
    float4 bs = *(const float4*)(b2 + f0);
#pragma unroll
    for (int j = 0; j < 4; ++j) {
      int e = eb + j * 16 + l15;
      ushort4 o;
      o.x = f2bf(fmaxf(acc[i][j][0] + bs.x, 0.f));
      o.y = f2bf(fmaxf(acc[i][j][1] + bs.y, 0.f));
      o.z = f2bf(fmaxf(acc[i][j][2] + bs.z, 0.f));
      o.w = f2bf(fmaxf(acc[i][j][3] + bs.w, 0.f));
      *(ushort4*)&h[HOFF(e, f0)] = o;  // h now holds h2 [edge][feat]
    }
  }
  __syncthreads();

  // ---- GEMM2: m^T = W3T @ h2^T ----
#pragma unroll
  for (int i = 0; i < 4; ++i)
#pragma unroll
    for (int j = 0; j < 4; ++j) { f32x4 z = {0.f, 0.f, 0.f, 0.f}; acc[i][j] = z; }
  for (int kc = 0; kc < 256; kc += 32) {
    short8 a[4], bq[4];
#pragma unroll
    for (int i = 0; i < 4; ++i)
      a[i] = *(const short8*)(W3T + (size_t)(fb + i * 16 + l15) * 256 + kc + q * 8);
#pragma unroll
    for (int j = 0; j < 4; ++j)
      bq[j] = *(const short8*)&h[HOFF(eb + j * 16 + l15, kc + q * 8)];
#pragma unroll
    for (int i = 0; i < 4; ++i)
#pragma unroll
      for (int j = 0; j < 4; ++j)
        acc[i][j] = __builtin_amdgcn_mfma_f32_16x16x32_bf16(a[i], bq[j], acc[i][j], 0, 0, 0);
  }
  // scatter-add into agg[dst] (+b3; relu deferred to after aggregation)
#pragma unroll
  for (int j = 0; j < 4; ++j) {
    int eg = e0 + eb + j * 16 + l15;
    int dn = dstI[eg];
    float* pr = agg + (size_t)dn * 256;
#pragma unroll
    for (int i = 0; i < 4; ++i) {
      int f0 = fb + i * 16 + q * 4;
      float4 bs = *(const float4*)(b3 + f0);
      atomicAdd(pr + f0 + 0, acc[i][j][0] + bs.x);
      atomicAdd(pr + f0 + 1, acc[i][j][1] + bs.y);
      atomicAdd(pr + f0 + 2, acc[i][j][2] + bs.z);
      atomicAdd(pr + f0 + 3, acc[i][j][3] + bs.w);
    }
  }
}

// ---------------- relu + layernorm, fp32 in -> bf16 out ----------------
__global__ void relu_ln(const float* __restrict__ agg, const float* __restrict__ g,
                        const float* __restrict__ b, unsigned short* __restrict__ out) {
  int row = blockIdx.x * 4 + (threadIdx.x >> 6);
  int lane = threadIdx.x & 63;
  if (row >= NN) return;
  float4 v = *(const float4*)(agg + (size_t)row * 256 + lane * 4);
  v.x = fmaxf(v.x, 0.f); v.y = fmaxf(v.y, 0.f); v.z = fmaxf(v.z, 0.f); v.w = fmaxf(v.w, 0.f);
  float s = v.x + v.y + v.z + v.w;
  float sq = v.x * v.x + v.y * v.y + v.z * v.z + v.w * v.w;
  for (int off = 32; off >= 1; off >>= 1) {
    s += __shfl_xor(s, off);
    sq += __shfl_xor(sq, off);
  }
  float mu = s * (1.f / 256.f);
  float var = sq * (1.f / 256.f) - mu * mu;
  float rs = rsqrtf(var + 1e-5f);
  float4 gg = *(const float4*)(g + lane * 4);
  float4 bb = *(const float4*)(b + lane * 4);
  ushort4 o;
  o.x = f2bf((v.x - mu) * rs * gg.x + bb.x);
  o.y = f2bf((v.y - mu) * rs * gg.y + bb.y);
  o.z = f2bf((v.z - mu) * rs * gg.z + bb.z);
  o.w = f2bf((v.w - mu) * rs * gg.w + bb.w);
  *(ushort4*)(out + (size_t)row * 256 + lane * 4) = o;
}

// ---------------- gumbel softmax + entropy/avg_s accumulation; s written fp32 to d_out ----------------
__global__ void gumbel_softmax(const float* __restrict__ logits, const float* __restrict__ u,
                               float* __restrict__ sf,
                               float* __restrict__ entacc, float* __restrict__ avgacc) {
  __shared__ float lavg[32];
  __shared__ float lent;
  int t = threadIdx.x;
  if (t < 32) lavg[t] = 0.f;
  if (t == 0) lent = 0.f;
  __syncthreads();
  int n = blockIdx.x * 256 + t;
  if (n < NN) {
    float z[32];
    float m = -1e30f;
#pragma unroll
    for (int k = 0; k < 8; ++k) {
      float4 lg = *(const float4*)(logits + (size_t)n * 32 + k * 4);
      float4 uu = *(const float4*)(u + (size_t)n * 32 + k * 4);
      float a0 = lg.x - logf(-logf(uu.x + 1e-9f) + 1e-9f);
      float a1 = lg.y - logf(-logf(uu.y + 1e-9f) + 1e-9f);
      float a2 = lg.z - logf(-logf(uu.z + 1e-9f) + 1e-9f);
      float a3 = lg.w - logf(-logf(uu.w + 1e-9f) + 1e-9f);
      z[k * 4 + 0] = a0; z[k * 4 + 1] = a1; z[k * 4 + 2] = a2; z[k * 4 + 3] = a3;
      m = fmaxf(m, fmaxf(fmaxf(a0, a1), fmaxf(a2, a3)));
    }
    float sum = 0.f;
#pragma unroll
    for (int j = 0; j < 32; ++j) { z[j] = expf(z[j] - m); sum += z[j]; }
    float inv = 1.f / sum;
    float ent = 0.f;
#pragma unroll
    for (int j = 0; j < 32; ++j) {
      float sj = z[j] * inv;
      sf[(size_t)n * 32 + j] = sj;
      ent += sj * logf(sj + 1e-9f);
      atomicAdd(&lavg[j], sj);
    }
    atomicAdd(&lent, ent);
  }
  __syncthreads();
  if (t < 32) atomicAdd(&avgacc[t], lavg[t]);
  if (t == 0) atomicAdd(entacc, lent);
}

// ---------------- batch segment bounds (batch is sorted) ----------------
__global__ void find_bounds(const int* __restrict__ batch, int* __restrict__ bstart) {
  int n = blockIdx.x * 256 + threadIdx.x;
  if (n >= NN) return;
  int bn = batch[n];
  if (n == 0) {
    for (int b2 = 0; b2 <= bn; ++b2) bstart[b2] = 0;
  } else {
    int bp = batch[n - 1];
    for (int b2 = bp + 1; b2 <= bn; ++b2) bstart[b2] = n;
  }
  if (n == NN - 1) {
    for (int b2 = bn + 1; b2 <= NBATCH; ++b2) bstart[b2] = NN;
  }
}

// ---------------- pooled[b,s,h] = sum_n x2[n,h]*s[n,s] ----------------
__global__ void pool_kernel(const unsigned short* __restrict__ x2b, const float* __restrict__ sf,
                            const int* __restrict__ bstart, float* __restrict__ pooled) {
  int b = blockIdx.x, ci = blockIdx.y;
  int n0b = bstart[b], n1b = bstart[b + 1];
  int t = threadIdx.x;
  int si = t >> 3;          // 0..31
  int hb = (t & 7) * 32;    // 0..224
  float acc[32];
#pragma unroll
  for (int k = 0; k < 32; ++k) acc[k] = 0.f;
  for (int nst = n0b + ci * 128; nst < n1b; nst += gridDim.y * 128) {
    int nend = (nst + 128 < n1b) ? nst + 128 : n1b;
    for (int n = nst; n < nend; ++n) {
      float sv = sf[(size_t)n * 32 + si];
      const unsigned short* xr = x2b + (size_t)n * 256 + hb;
#pragma unroll
      for (int k2 = 0; k2 < 4; ++k2) {
        short8 xv = *(const short8*)(xr + k2 * 8);
#pragma unroll
        for (int jj = 0; jj < 8; ++jj) acc[k2 * 8 + jj] = fmaf(sv, bf2fs(xv[jj]), acc[k2 * 8 + jj]);
      }
    }
  }
  float* pp = pooled + (size_t)(b * 32 + si) * 256 + hb;
#pragma unroll
  for (int k = 0; k < 32; ++k) atomicAdd(pp + k, acc[k]);
}

__global__ void cast_kernel(const float* __restrict__ in, unsigned short* __restrict__ out, int n) {
  int i = blockIdx.x * 256 + threadIdx.x;
  if (i < n) out[i] = f2bf(in[i]);
}

__global__ void loss_kernel(const float* __restrict__ accs, float* __restrict__ outloss) {
  int t = threadIdx.x;
  float d = 0.f;
  if (t < 32) {
    float a = accs[16 + t] * (1.f / NN);
    d = a * logf(a + 1e-9f);
  }
  for (int off = 32; off >= 1; off >>= 1) d += __shfl_xor(d, off);
  if (t == 0) {
    float ent = -accs[0] * (1.f / NN);
    outloss[0] = ent + d;
  }
}

// ---------------- orchestration ----------------
extern "C" void kernel_launch(void* const* d_in, const int* in_sizes, int n_in,
                              void* d_out, int out_size, void* d_ws, size_t ws_size,
                              hipStream_t stream) {
  (void)in_sizes; (void)n_in; (void)out_size; (void)ws_size;
  // Inputs are fp32 (reference dtypes); indices int32. Outputs are fp32.
  const float* x = (const float*)d_in[0];
  const float* u = (const float*)d_in[1];
  const int* ei = (const int*)d_in[2];
  const int* batch = (const int*)d_in[3];
  const float* g1w1 = (const float*)d_in[4];
  const float* g1b1 = (const float*)d_in[5];
  const float* g1w2 = (const float*)d_in[6];
  const float* g1b2 = (const float*)d_in[7];
  const float* g1w3 = (const float*)d_in[8];
  const float* g1b3 = (const float*)d_in[9];
  const float* ln1g = (const float*)d_in[10];
  const float* ln1b = (const float*)d_in[11];
  const float* g2w1 = (const float*)d_in[12];
  const float* g2b1 = (const float*)d_in[13];
  const float* g2w2 = (const float*)d_in[14];
  const float* g2b2 = (const float*)d_in[15];
  const float* g2w3 = (const float*)d_in[16];
  const float* g2b3 = (const float*)d_in[17];
  const float* ln2g = (const float*)d_in[18];
  const float* ln2b = (const float*)d_in[19];
  const float* aw1 = (const float*)d_in[20];
  const float* ab1 = (const float*)d_in[21];
  const float* aw2 = (const float*)d_in[22];
  const float* ab2 = (const float*)d_in[23];
  const float* ow1 = (const float*)d_in[24];
  const float* ob1 = (const float*)d_in[25];
  const float* ow2 = (const float*)d_in[26];
  const float* ob2 = (const float*)d_in[27];
  const int* srcI = ei;        // edge_index[0] = src
  const int* dstI = ei + NE;   // edge_index[1] = dst

  char* wp = (char*)d_ws;
  size_t off = 0;
  auto alloc = [&](size_t bytes) {
    void* p = wp + off;
    off += (bytes + 255) & ~(size_t)255;
    return p;
  };
  unsigned short* W1catT = (unsigned short*)alloc((size_t)512 * 64 * 2);
  unsigned short* W2catT = (unsigned short*)alloc((size_t)512 * 256 * 2);
  unsigned short* g1w2T = (unsigned short*)alloc((size_t)256 * 256 * 2);
  unsigned short* g1w3T = (unsigned short*)alloc((size_t)256 * 256 * 2);
  unsigned short* g2w2T = (unsigned short*)alloc((size_t)256 * 256 * 2);
  unsigned short* g2w3T = (unsigned short*)alloc((size_t)256 * 256 * 2);
  unsigned short* aw1T = (unsigned short*)alloc((size_t)256 * 256 * 2);
  unsigned short* aw2T = (unsigned short*)alloc((size_t)32 * 256 * 2);
  unsigned short* ow1T = (unsigned short*)alloc((size_t)256 * 256 * 2);
  unsigned short* ow2T = (unsigned short*)alloc((size_t)128 * 256 * 2);
  unsigned short* xb = (unsigned short*)alloc((size_t)NN * 64 * 2);
  unsigned short* PQ = (unsigned short*)alloc((size_t)NN * 512 * 2);
  float* agg = (float*)alloc((size_t)NN * 256 * 4);
  unsigned short* x1b = (unsigned short*)alloc((size_t)NN * 256 * 2);
  unsigned short* x2b = (unsigned short*)alloc((size_t)NN * 256 * 2);
  unsigned short* assh = (unsigned short*)alloc((size_t)NN * 256 * 2);
  float* logits = (float*)alloc((size_t)NN * 32 * 4);
  float* pooled = (float*)alloc((size_t)512 * 256 * 4);
  unsigned short* pooledb = (unsigned short*)alloc((size_t)512 * 256 * 2);
  unsigned short* hidB = (unsigned short*)alloc((size_t)512 * 256 * 2);
  int* bstart = (int*)alloc(32 * 4);
  float* accs = (float*)alloc(64 * 4);

  float* out_f = (float*)d_out;
  float* out_latent = out_f;                 // [16*32*128] = 65536
  float* out_s = out_f + 65536;              // [20000*32]
  float* out_loss = out_f + 65536 + 640000;  // [1]

  TDs tds;
  tds.t[0] = {g1w1, W1catT, 64, 256, 0, 256};
  tds.t[1] = {g1w1, W1catT + 256 * 64, 64, 256, 64, 256};
  tds.t[2] = {g1w2, g1w2T, 256, 256, 0, 256};
  tds.t[3] = {g1w3, g1w3T, 256, 256, 0, 256};
  tds.t[4] = {g2w1, W2catT, 256, 256, 0, 256};
  tds.t[5] = {g2w1, W2catT + 256 * 256, 256, 256, 256, 256};
  tds.t[6] = {g2w2, g2w2T, 256, 256, 0, 256};
  tds.t[7] = {g2w3, g2w3T, 256, 256, 0, 256};
  tds.t[8] = {aw1, aw1T, 256, 256, 0, 256};
  tds.t[9] = {aw2, aw2T, 256, 32, 0, 32};
  tds.t[10] = {ow1, ow1T, 256, 256, 0, 256};
  tds.t[11] = {ow2, ow2T, 256, 128, 0, 128};
  tds.t[12] = {x, xb, NN * 64, 1, 0, 0};

  wprep<<<dim3(128, 13), 256, 0, stream>>>(tds);
  (void)hipMemsetAsync(agg, 0, (size_t)NN * 256 * 4, stream);
  (void)hipMemsetAsync(accs, 0, 64 * 4, stream);
  (void)hipMemsetAsync(pooled, 0, (size_t)512 * 256 * 4, stream);

  // layer 1: PQ = x @ [W1_dst | W1_src]
  gemmT<0><<<dim3(2, 157), 512, 0, stream>>>(W1catT, xb, nullptr, PQ, NN, 64, 512, 512);
  edge_mlp<<<dim3(2500), 512, 0, stream>>>(PQ, srcI, dstI, g1b1, g1w2T, g1b2, g1w3T, g1b3, agg);
  relu_ln<<<dim3(5000), 256, 0, stream>>>(agg, ln1g, ln1b, x1b);
  (void)hipMemsetAsync(agg, 0, (size_t)NN * 256 * 4, stream);

  // layer 2
  gemmT<0><<<dim3(2, 157), 512, 0, stream>>>(W2catT, x1b, nullptr, PQ, NN, 256, 512, 512);
  edge_mlp<<<dim3(2500), 512, 0, stream>>>(PQ, srcI, dstI, g2b1, g2w2T, g2b2, g2w3T, g2b3, agg);
  relu_ln<<<dim3(5000), 256, 0, stream>>>(agg, ln2g, ln2b, x2b);

  // assignment MLP + gumbel softmax (s written fp32 directly to d_out)
  gemmT<1><<<dim3(1, 157), 512, 0, stream>>>(aw1T, x2b, ab1, assh, NN, 256, 256, 256);
  gemmT<2><<<dim3(1, 157), 512, 0, stream>>>(aw2T, assh, ab2, logits, NN, 256, 32, 32);
  gumbel_softmax<<<dim3(79), 256, 0, stream>>>(logits, u, out_s, accs, accs + 16);

  // pooling + output MLP (latent fp32 to d_out)
  find_bounds<<<dim3(79), 256, 0, stream>>>(batch, bstart);
  pool_kernel<<<dim3(16, 12), 256, 0, stream>>>(x2b, out_s, bstart, pooled);
  cast_kernel<<<dim3(512), 256, 0, stream>>>(pooled, pooledb, 512 * 256);
  gemmT<1><<<dim3(1, 4), 512, 0, stream>>>(ow1T, pooledb, ob1, hidB, 512, 256, 256, 256);
  gemmT<2><<<dim3(1, 4), 512, 0, stream>>>(ow2T, hidB, ob2, out_latent, 512, 256, 128, 128);
  loss_kernel<<<dim3(1), 64, 0, stream>>>(accs, out_loss);
}

// Round 5
// 1159.148 us; speedup vs baseline: 2.3208x; 2.3208x over previous
//
#include <hip/hip_runtime.h>
#include <stdint.h>

#define NN 20000      // nodes
#define NE 320000     // edges
#define NBATCH 16

typedef short short8 __attribute__((ext_vector_type(8)));   // 8 x bf16 bits (4 VGPR)
typedef float f32x4  __attribute__((ext_vector_type(4)));   // MFMA acc

__device__ __forceinline__ unsigned short f2bf(float f) {
  union { float f; unsigned u; } v; v.f = f;
  unsigned r = v.u + 0x7FFFu + ((v.u >> 16) & 1u);   // RNE
  return (unsigned short)(r >> 16);
}
__device__ __forceinline__ float bf2f(unsigned short h) {
  union { unsigned u; float f; } v; v.u = ((unsigned)h) << 16;
  return v.f;
}
__device__ __forceinline__ float bf2fs(short h) { return bf2f((unsigned short)h); }

// LDS tile: 128 edges x 256 bf16, XOR-swizzled 16B granules, exactly 64 KB.
#define HOFF(e, k) (((e) << 8) + (((((k) >> 3) ^ ((e) & 7)) << 3) + ((k) & 7)))

// ---------------- weight prep: fp32 [K,N] -> bf16 transposed [N,K] (or plain cast) ----------------
struct TD { const float* s; unsigned short* d; int R, C, r0, ld; };
struct TDs { TD t[13]; };

__global__ void wprep(TDs all) {
  TD td = all.t[blockIdx.y];
  int stride = gridDim.x * blockDim.x;
  int i0 = blockIdx.x * blockDim.x + threadIdx.x;
  if (td.ld == 0) {                       // plain cast copy
    for (int i = i0; i < td.R; i += stride) td.d[i] = f2bf(td.s[i]);
  } else {                                // dst[c*R + r] = src[(r0+r)*ld + c]
    int total = td.R * td.C;
    for (int i = i0; i < total; i += stride) {
      int c = i / td.R;
      int r = i - c * td.R;
      td.d[i] = f2bf(td.s[(size_t)(td.r0 + r) * td.ld + c]);
    }
  }
}

// ---------------- CSR build (dst-sorted edge permutation) ----------------
__global__ void hist_kernel(const int* __restrict__ dstI, int* __restrict__ deg) {
  int e = blockIdx.x * 256 + threadIdx.x;
  if (e < NE) atomicAdd(&deg[dstI[e]], 1);
}

__global__ void scan_deg(const int* __restrict__ deg, int* __restrict__ rowstart,
                         int* __restrict__ cursor) {
  __shared__ int part[256];
  int t = threadIdx.x;
  int c0 = t * 80; if (c0 > NN) c0 = NN;
  int c1 = c0 + 80; if (c1 > NN) c1 = NN;
  int s = 0;
  for (int i = c0; i < c1; ++i) s += deg[i];
  part[t] = s;
  __syncthreads();
  if (t == 0) {
    int run = 0;
    for (int i = 0; i < 256; ++i) { int v = part[i]; part[i] = run; run += v; }
  }
  __syncthreads();
  int run = part[t];
  for (int i = c0; i < c1; ++i) { rowstart[i] = run; cursor[i] = run; run += deg[i]; }
  if (t == 255) rowstart[NN] = run;   // == NE
}

__global__ void fillcsr(const int* __restrict__ srcI, const int* __restrict__ dstI,
                        int* __restrict__ cursor, int* __restrict__ sSrc,
                        int* __restrict__ sDst) {
  int e = blockIdx.x * 256 + threadIdx.x;
  if (e < NE) {
    int d = dstI[e];
    int slot = atomicAdd(&cursor[d], 1);
    sDst[slot] = d;
    sSrc[slot] = srcI[e];
  }
}

// ---------------- generic transposed-weight GEMM: Out[r][f] = In[r][:] . WT[f][:] ----------------
template <int EPI>  // 0: bf16 store (+bias), 1: bf16 relu(+bias), 2: f32 store (+bias)
__global__ __launch_bounds__(512, 4) void gemmT(
    const unsigned short* __restrict__ WT, const unsigned short* __restrict__ In,
    const float* __restrict__ bias, void* __restrict__ Out,
    int M, int K, int Nout, int ldo) {
  const int tid = threadIdx.x;
  const int lane = tid & 63, w = tid >> 6;
  const int wf = w >> 1, we = w & 1;
  const int l15 = lane & 15, q = lane >> 4;
  const int fb = blockIdx.x * 256 + wf * 64;
  const int rb = blockIdx.y * 128 + we * 64;
  f32x4 acc[4][4] = {};
  const short8 zz = {0, 0, 0, 0, 0, 0, 0, 0};
  for (int kc = 0; kc < K; kc += 32) {
    short8 a[4], bq[4];
#pragma unroll
    for (int i = 0; i < 4; ++i) {
      if (fb + i * 16 < Nout)
        a[i] = *(const short8*)(WT + (size_t)(fb + i * 16 + l15) * K + kc + q * 8);
      else
        a[i] = zz;
      int r = rb + i * 16 + l15;
      if (r >= M) r = M - 1;  // clamp: stores guarded below
      bq[i] = *(const short8*)(In + (size_t)r * K + kc + q * 8);
    }
#pragma unroll
    for (int i = 0; i < 4; ++i)
#pragma unroll
      for (int j = 0; j < 4; ++j)
        acc[i][j] = __builtin_amdgcn_mfma_f32_16x16x32_bf16(a[i], bq[j], acc[i][j], 0, 0, 0);
  }
#pragma unroll
  for (int i = 0; i < 4; ++i) {
    int f0 = fb + i * 16 + q * 4;
    if (f0 >= Nout) continue;
    float4 bs = make_float4(0.f, 0.f, 0.f, 0.f);
    if (bias) bs = *(const float4*)(bias + f0);
#pragma unroll
    for (int j = 0; j < 4; ++j) {
      int r = rb + j * 16 + l15;
      if (r >= M) continue;
      float v0 = acc[i][j][0] + bs.x;
      float v1 = acc[i][j][1] + bs.y;
      float v2 = acc[i][j][2] + bs.z;
      float v3 = acc[i][j][3] + bs.w;
      if (EPI == 1) {
        v0 = fmaxf(v0, 0.f); v1 = fmaxf(v1, 0.f); v2 = fmaxf(v2, 0.f); v3 = fmaxf(v3, 0.f);
      }
      if (EPI == 2) {
        *(float4*)((float*)Out + (size_t)r * ldo + f0) = make_float4(v0, v1, v2, v3);
      } else {
        ushort4 o;
        o.x = f2bf(v0); o.y = f2bf(v1); o.z = f2bf(v2); o.w = f2bf(v3);
        *(ushort4*)((unsigned short*)Out + (size_t)r * ldo + f0) = o;
      }
    }
  }
}

// ---------------- fused per-edge MLP, sorted edges, streams m (NO atomics) ----------------
// h1 = relu(PQ[sDst][0:256] + PQ[sSrc][256:512] + b1)   (LDS, 128 sorted edges)
// h2 = relu(h1 @ W2 + b2)                                (LDS, overwrite)
// m[slot] = h2 @ W3        (bf16, b3 deferred to agg_ln) (coalesced stream via LDS bounce)
__global__ __launch_bounds__(512, 4) void edge_mlp_sorted(
    const unsigned short* __restrict__ PQ, const int* __restrict__ sSrc,
    const int* __restrict__ sDst, const float* __restrict__ b1,
    const unsigned short* __restrict__ W2T, const float* __restrict__ b2,
    const unsigned short* __restrict__ W3T, unsigned short* __restrict__ m) {
  __shared__ __align__(16) unsigned short h[128 * 256];  // 64 KB, swizzled
  const int tid = threadIdx.x;
  const int e0 = blockIdx.x * 128;

  {  // phase 0: gather + h1
    int r = tid >> 2;
    int c0 = (tid & 3) * 64;
    int dn = sDst[e0 + r];
    int sn = sSrc[e0 + r];
    const unsigned short* pd = PQ + (size_t)dn * 512 + c0;
    const unsigned short* ps = PQ + (size_t)sn * 512 + 256 + c0;
    const float* bp = b1 + c0;
#pragma unroll
    for (int i = 0; i < 8; ++i) {
      short8 dv = *(const short8*)(pd + i * 8);
      short8 sv = *(const short8*)(ps + i * 8);
      float4 bA = *(const float4*)(bp + i * 8);
      float4 bB = *(const float4*)(bp + i * 8 + 4);
      float bb[8] = {bA.x, bA.y, bA.z, bA.w, bB.x, bB.y, bB.z, bB.w};
      short8 o;
#pragma unroll
      for (int j = 0; j < 8; ++j) {
        float v = bf2fs(dv[j]) + bf2fs(sv[j]) + bb[j];
        o[j] = (short)f2bf(fmaxf(v, 0.f));
      }
      *(short8*)&h[HOFF(r, c0 + i * 8)] = o;
    }
  }
  __syncthreads();

  const int lane = tid & 63, w = tid >> 6;
  const int wf = w >> 1, we = w & 1;
  const int l15 = lane & 15, q = lane >> 4;
  const int fb = wf * 64, eb = we * 64;
  f32x4 acc[4][4];

  // ---- GEMM1: h2^T = W2T @ h1^T ----
#pragma unroll
  for (int i = 0; i < 4; ++i)
#pragma unroll
    for (int j = 0; j < 4; ++j) { f32x4 z = {0.f, 0.f, 0.f, 0.f}; acc[i][j] = z; }
  for (int kc = 0; kc < 256; kc += 32) {
    short8 a[4], bq[4];
#pragma unroll
    for (int i = 0; i < 4; ++i)
      a[i] = *(const short8*)(W2T + (size_t)(fb + i * 16 + l15) * 256 + kc + q * 8);
#pragma unroll
    for (int j = 0; j < 4; ++j)
      bq[j] = *(const short8*)&h[HOFF(eb + j * 16 + l15, kc + q * 8)];
#pragma unroll
    for (int i = 0; i < 4; ++i)
#pragma unroll
      for (int j = 0; j < 4; ++j)
        acc[i][j] = __builtin_amdgcn_mfma_f32_16x16x32_bf16(a[i], bq[j], acc[i][j], 0, 0, 0);
  }
  __syncthreads();  // all reads of h1 done
#pragma unroll
  for (int i = 0; i < 4; ++i) {
    int f0 = fb + i * 16 + q * 4;
    float4 bs = *(const float4*)(b2 + f0);
#pragma unroll
    for (int j = 0; j < 4; ++j) {
      int e = eb + j * 16 + l15;
      ushort4 o;
      o.x = f2bf(fmaxf(acc[i][j][0] + bs.x, 0.f));
      o.y = f2bf(fmaxf(acc[i][j][1] + bs.y, 0.f));
      o.z = f2bf(fmaxf(acc[i][j][2] + bs.z, 0.f));
      o.w = f2bf(fmaxf(acc[i][j][3] + bs.w, 0.f));
      *(ushort4*)&h[HOFF(e, f0)] = o;  // h now holds h2 [edge][feat]
    }
  }
  __syncthreads();

  // ---- GEMM2: m^T = W3T @ h2^T ----
#pragma unroll
  for (int i = 0; i < 4; ++i)
#pragma unroll
    for (int j = 0; j < 4; ++j) { f32x4 z = {0.f, 0.f, 0.f, 0.f}; acc[i][j] = z; }
  for (int kc = 0; kc < 256; kc += 32) {
    short8 a[4], bq[4];
#pragma unroll
    for (int i = 0; i < 4; ++i)
      a[i] = *(const short8*)(W3T + (size_t)(fb + i * 16 + l15) * 256 + kc + q * 8);
#pragma unroll
    for (int j = 0; j < 4; ++j)
      bq[j] = *(const short8*)&h[HOFF(eb + j * 16 + l15, kc + q * 8)];
#pragma unroll
    for (int i = 0; i < 4; ++i)
#pragma unroll
      for (int j = 0; j < 4; ++j)
        acc[i][j] = __builtin_amdgcn_mfma_f32_16x16x32_bf16(a[i], bq[j], acc[i][j], 0, 0, 0);
  }
  __syncthreads();  // all reads of h2 done before overwrite
#pragma unroll
  for (int i = 0; i < 4; ++i) {
    int f0 = fb + i * 16 + q * 4;
#pragma unroll
    for (int j = 0; j < 4; ++j) {
      int e = eb + j * 16 + l15;
      ushort4 o;
      o.x = f2bf(acc[i][j][0]); o.y = f2bf(acc[i][j][1]);
      o.z = f2bf(acc[i][j][2]); o.w = f2bf(acc[i][j][3]);
      *(ushort4*)&h[HOFF(e, f0)] = o;  // h now holds m [edge][feat]
    }
  }
  __syncthreads();
  {  // coalesced dump to global m
    int r = tid >> 2;
    int c0 = (tid & 3) * 64;
    unsigned short* mp = m + (size_t)(e0 + r) * 256 + c0;
#pragma unroll
    for (int i = 0; i < 8; ++i)
      *(short8*)(mp + i * 8) = *(short8*)&h[HOFF(r, c0 + i * 8)];
  }
}

// ---------------- fallback: fused per-edge MLP with atomic scatter (round-4 path) ----------------
__global__ __launch_bounds__(512, 4) void edge_mlp_atomic(
    const unsigned short* __restrict__ PQ, const int* __restrict__ srcI,
    const int* __restrict__ dstI, const float* __restrict__ b1,
    const unsigned short* __restrict__ W2T, const float* __restrict__ b2,
    const unsigned short* __restrict__ W3T, const float* __restrict__ b3,
    float* __restrict__ agg) {
  __shared__ __align__(16) unsigned short h[128 * 256];
  const int tid = threadIdx.x;
  const int e0 = blockIdx.x * 128;
  {
    int r = tid >> 2;
    int c0 = (tid & 3) * 64;
    int dn = dstI[e0 + r];
    int sn = srcI[e0 + r];
    const unsigned short* pd = PQ + (size_t)dn * 512 + c0;
    const unsigned short* ps = PQ + (size_t)sn * 512 + 256 + c0;
    const float* bp = b1 + c0;
#pragma unroll
    for (int i = 0; i < 8; ++i) {
      short8 dv = *(const short8*)(pd + i * 8);
      short8 sv = *(const short8*)(ps + i * 8);
      float4 bA = *(const float4*)(bp + i * 8);
      float4 bB = *(const float4*)(bp + i * 8 + 4);
      float bb[8] = {bA.x, bA.y, bA.z, bA.w, bB.x, bB.y, bB.z, bB.w};
      short8 o;
#pragma unroll
      for (int j = 0; j < 8; ++j) {
        float v = bf2fs(dv[j]) + bf2fs(sv[j]) + bb[j];
        o[j] = (short)f2bf(fmaxf(v, 0.f));
      }
      *(short8*)&h[HOFF(r, c0 + i * 8)] = o;
    }
  }
  __syncthreads();
  const int lane = tid & 63, w = tid >> 6;
  const int wf = w >> 1, we = w & 1;
  const int l15 = lane & 15, q = lane >> 4;
  const int fb = wf * 64, eb = we * 64;
  f32x4 acc[4][4];
#pragma unroll
  for (int i = 0; i < 4; ++i)
#pragma unroll
    for (int j = 0; j < 4; ++j) { f32x4 z = {0.f, 0.f, 0.f, 0.f}; acc[i][j] = z; }
  for (int kc = 0; kc < 256; kc += 32) {
    short8 a[4], bq[4];
#pragma unroll
    for (int i = 0; i < 4; ++i)
      a[i] = *(const short8*)(W2T + (size_t)(fb + i * 16 + l15) * 256 + kc + q * 8);
#pragma unroll
    for (int j = 0; j < 4; ++j)
      bq[j] = *(const short8*)&h[HOFF(eb + j * 16 + l15, kc + q * 8)];
#pragma unroll
    for (int i = 0; i < 4; ++i)
#pragma unroll
      for (int j = 0; j < 4; ++j)
        acc[i][j] = __builtin_amdgcn_mfma_f32_16x16x32_bf16(a[i], bq[j], acc[i][j], 0, 0, 0);
  }
  __syncthreads();
#pragma unroll
  for (int i = 0; i < 4; ++i) {
    int f0 = fb + i * 16 + q * 4;
    float4 bs = *(const float4*)(b2 + f0);
#pragma unroll
    for (int j = 0; j < 4; ++j) {
      int e = eb + j * 16 + l15;
      ushort4 o;
      o.x = f2bf(fmaxf(acc[i][j][0] + bs.x, 0.f));
      o.y = f2bf(fmaxf(acc[i][j][1] + bs.y, 0.f));
      o.z = f2bf(fmaxf(acc[i][j][2] + bs.z, 0.f));
      o.w = f2bf(fmaxf(acc[i][j][3] + bs.w, 0.f));
      *(ushort4*)&h[HOFF(e, f0)] = o;
    }
  }
  __syncthreads();
#pragma unroll
  for (int i = 0; i < 4; ++i)
#pragma unroll
    for (int j = 0; j < 4; ++j) { f32x4 z = {0.f, 0.f, 0.f, 0.f}; acc[i][j] = z; }
  for (int kc = 0; kc < 256; kc += 32) {
    short8 a[4], bq[4];
#pragma unroll
    for (int i = 0; i < 4; ++i)
      a[i] = *(const short8*)(W3T + (size_t)(fb + i * 16 + l15) * 256 + kc + q * 8);
#pragma unroll
    for (int j = 0; j < 4; ++j)
      bq[j] = *(const short8*)&h[HOFF(eb + j * 16 + l15, kc + q * 8)];
#pragma unroll
    for (int i = 0; i < 4; ++i)
#pragma unroll
      for (int j = 0; j < 4; ++j)
        acc[i][j] = __builtin_amdgcn_mfma_f32_16x16x32_bf16(a[i], bq[j], acc[i][j], 0, 0, 0);
  }
#pragma unroll
  for (int j = 0; j < 4; ++j) {
    int eg = e0 + eb + j * 16 + l15;
    int dn = dstI[eg];
    float* pr = agg + (size_t)dn * 256;
#pragma unroll
    for (int i = 0; i < 4; ++i) {
      int f0 = fb + i * 16 + q * 4;
      float4 bs = *(const float4*)(b3 + f0);
      atomicAdd(pr + f0 + 0, acc[i][j][0] + bs.x);
      atomicAdd(pr + f0 + 1, acc[i][j][1] + bs.y);
      atomicAdd(pr + f0 + 2, acc[i][j][2] + bs.z);
      atomicAdd(pr + f0 + 3, acc[i][j][3] + bs.w);
    }
  }
}

// ---------------- aggregate sorted m runs + deg*b3, relu + layernorm -> bf16 ----------------
// one wave per node; lane handles 4 features
__global__ __launch_bounds__(256) void agg_ln(
    const unsigned short* __restrict__ m, const int* __restrict__ rowstart,
    const float* __restrict__ b3, const float* __restrict__ g,
    const float* __restrict__ b, unsigned short* __restrict__ out) {
  int n = blockIdx.x * 4 + (threadIdx.x >> 6);
  int lane = threadIdx.x & 63;
  if (n >= NN) return;
  int r0 = rowstart[n], r1 = rowstart[n + 1];
  float a0 = 0.f, a1 = 0.f, a2 = 0.f, a3 = 0.f;
  for (int r = r0; r < r1; ++r) {
    ushort4 v = *(const ushort4*)(m + (size_t)r * 256 + lane * 4);
    a0 += bf2f(v.x); a1 += bf2f(v.y); a2 += bf2f(v.z); a3 += bf2f(v.w);
  }
  float4 b3v = *(const float4*)(b3 + lane * 4);
  float degf = (float)(r1 - r0);
  a0 = fmaxf(a0 + degf * b3v.x, 0.f);
  a1 = fmaxf(a1 + degf * b3v.y, 0.f);
  a2 = fmaxf(a2 + degf * b3v.z, 0.f);
  a3 = fmaxf(a3 + degf * b3v.w, 0.f);
  float s = a0 + a1 + a2 + a3;
  float sq = a0 * a0 + a1 * a1 + a2 * a2 + a3 * a3;
  for (int off = 32; off >= 1; off >>= 1) {
    s += __shfl_xor(s, off);
    sq += __shfl_xor(sq, off);
  }
  float mu = s * (1.f / 256.f);
  float var = sq * (1.f / 256.f) - mu * mu;
  float rs = rsqrtf(var + 1e-5f);
  float4 gg = *(const float4*)(g + lane * 4);
  float4 bb = *(const float4*)(b + lane * 4);
  ushort4 o;
  o.x = f2bf((a0 - mu) * rs * gg.x + bb.x);
  o.y = f2bf((a1 - mu) * rs * gg.y + bb.y);
  o.z = f2bf((a2 - mu) * rs * gg.z + bb.z);
  o.w = f2bf((a3 - mu) * rs * gg.w + bb.w);
  *(ushort4*)(out + (size_t)n * 256 + lane * 4) = o;
}

// ---------------- relu + layernorm, fp32 in -> bf16 out (fallback path) ----------------
__global__ void relu_ln(const float* __restrict__ agg, const float* __restrict__ g,
                        const float* __restrict__ b, unsigned short* __restrict__ out) {
  int row = blockIdx.x * 4 + (threadIdx.x >> 6);
  int lane = threadIdx.x & 63;
  if (row >= NN) return;
  float4 v = *(const float4*)(agg + (size_t)row * 256 + lane * 4);
  v.x = fmaxf(v.x, 0.f); v.y = fmaxf(v.y, 0.f); v.z = fmaxf(v.z, 0.f); v.w = fmaxf(v.w, 0.f);
  float s = v.x + v.y + v.z + v.w;
  float sq = v.x * v.x + v.y * v.y + v.z * v.z + v.w * v.w;
  for (int off = 32; off >= 1; off >>= 1) {
    s += __shfl_xor(s, off);
    sq += __shfl_xor(sq, off);
  }
  float mu = s * (1.f / 256.f);
  float var = sq * (1.f / 256.f) - mu * mu;
  float rs = rsqrtf(var + 1e-5f);
  float4 gg = *(const float4*)(g + lane * 4);
  float4 bb = *(const float4*)(b + lane * 4);
  ushort4 o;
  o.x = f2bf((v.x - mu) * rs * gg.x + bb.x);
  o.y = f2bf((v.y - mu) * rs * gg.y + bb.y);
  o.z = f2bf((v.z - mu) * rs * gg.z + bb.z);
  o.w = f2bf((v.w - mu) * rs * gg.w + bb.w);
  *(ushort4*)(out + (size_t)row * 256 + lane * 4) = o;
}

// ---------------- gumbel softmax + entropy/avg_s accumulation; s written fp32 to d_out ----------------
__global__ void gumbel_softmax(const float* __restrict__ logits, const float* __restrict__ u,
                               float* __restrict__ sf,
                               float* __restrict__ entacc, float* __restrict__ avgacc) {
  __shared__ float lavg[32];
  __shared__ float lent;
  int t = threadIdx.x;
  if (t < 32) lavg[t] = 0.f;
  if (t == 0) lent = 0.f;
  __syncthreads();
  int n = blockIdx.x * 256 + t;
  if (n < NN) {
    float z[32];
    float m = -1e30f;
#pragma unroll
    for (int k = 0; k < 8; ++k) {
      float4 lg = *(const float4*)(logits + (size_t)n * 32 + k * 4);
      float4 uu = *(const float4*)(u + (size_t)n * 32 + k * 4);
      float a0 = lg.x - logf(-logf(uu.x + 1e-9f) + 1e-9f);
      float a1 = lg.y - logf(-logf(uu.y + 1e-9f) + 1e-9f);
      float a2 = lg.z - logf(-logf(uu.z + 1e-9f) + 1e-9f);
      float a3 = lg.w - logf(-logf(uu.w + 1e-9f) + 1e-9f);
      z[k * 4 + 0] = a0; z[k * 4 + 1] = a1; z[k * 4 + 2] = a2; z[k * 4 + 3] = a3;
      m = fmaxf(m, fmaxf(fmaxf(a0, a1), fmaxf(a2, a3)));
    }
    float sum = 0.f;
#pragma unroll
    for (int j = 0; j < 32; ++j) { z[j] = expf(z[j] - m); sum += z[j]; }
    float inv = 1.f / sum;
    float ent = 0.f;
#pragma unroll
    for (int j = 0; j < 32; ++j) {
      float sj = z[j] * inv;
      sf[(size_t)n * 32 + j] = sj;
      ent += sj * logf(sj + 1e-9f);
      atomicAdd(&lavg[j], sj);
    }
    atomicAdd(&lent, ent);
  }
  __syncthreads();
  if (t < 32) atomicAdd(&avgacc[t], lavg[t]);
  if (t == 0) atomicAdd(entacc, lent);
}

// ---------------- batch segment bounds (batch is sorted) ----------------
__global__ void find_bounds(const int* __restrict__ batch, int* __restrict__ bstart) {
  int n = blockIdx.x * 256 + threadIdx.x;
  if (n >= NN) return;
  int bn = batch[n];
  if (n == 0) {
    for (int b2 = 0; b2 <= bn; ++b2) bstart[b2] = 0;
  } else {
    int bp = batch[n - 1];
    for (int b2 = bp + 1; b2 <= bn; ++b2) bstart[b2] = n;
  }
  if (n == NN - 1) {
    for (int b2 = bn + 1; b2 <= NBATCH; ++b2) bstart[b2] = NN;
  }
}

// ---------------- pooled[b,s,h] = sum_n x2[n,h]*s[n,s] ----------------
__global__ void pool_kernel(const unsigned short* __restrict__ x2b, const float* __restrict__ sf,
                            const int* __restrict__ bstart, float* __restrict__ pooled) {
  int b = blockIdx.x, ci = blockIdx.y;
  int n0b = bstart[b], n1b = bstart[b + 1];
  int t = threadIdx.x;
  int si = t >> 3;          // 0..31
  int hb = (t & 7) * 32;    // 0..224
  float acc[32];
#pragma unroll
  for (int k = 0; k < 32; ++k) acc[k] = 0.f;
  for (int nst = n0b + ci * 128; nst < n1b; nst += gridDim.y * 128) {
    int nend = (nst + 128 < n1b) ? nst + 128 : n1b;
    for (int n = nst; n < nend; ++n) {
      float sv = sf[(size_t)n * 32 + si];
      const unsigned short* xr = x2b + (size_t)n * 256 + hb;
#pragma unroll
      for (int k2 = 0; k2 < 4; ++k2) {
        short8 xv = *(const short8*)(xr + k2 * 8);
#pragma unroll
        for (int jj = 0; jj < 8; ++jj) acc[k2 * 8 + jj] = fmaf(sv, bf2fs(xv[jj]), acc[k2 * 8 + jj]);
      }
    }
  }
  float* pp = pooled + (size_t)(b * 32 + si) * 256 + hb;
#pragma unroll
  for (int k = 0; k < 32; ++k) atomicAdd(pp + k, acc[k]);
}

__global__ void cast_kernel(const float* __restrict__ in, unsigned short* __restrict__ out, int n) {
  int i = blockIdx.x * 256 + threadIdx.x;
  if (i < n) out[i] = f2bf(in[i]);
}

__global__ void loss_kernel(const float* __restrict__ accs, float* __restrict__ outloss) {
  int t = threadIdx.x;
  float d = 0.f;
  if (t < 32) {
    float a = accs[16 + t] * (1.f / NN);
    d = a * logf(a + 1e-9f);
  }
  for (int off = 32; off >= 1; off >>= 1) d += __shfl_xor(d, off);
  if (t == 0) {
    float ent = -accs[0] * (1.f / NN);
    outloss[0] = ent + d;
  }
}

// ---------------- orchestration ----------------
extern "C" void kernel_launch(void* const* d_in, const int* in_sizes, int n_in,
                              void* d_out, int out_size, void* d_ws, size_t ws_size,
                              hipStream_t stream) {
  (void)in_sizes; (void)n_in; (void)out_size;
  const float* x = (const float*)d_in[0];
  const float* u = (const float*)d_in[1];
  const int* ei = (const int*)d_in[2];
  const int* batch = (const int*)d_in[3];
  const float* g1w1 = (const float*)d_in[4];
  const float* g1b1 = (const float*)d_in[5];
  const float* g1w2 = (const float*)d_in[6];
  const float* g1b2 = (const float*)d_in[7];
  const float* g1w3 = (const float*)d_in[8];
  const float* g1b3 = (const float*)d_in[9];
  const float* ln1g = (const float*)d_in[10];
  const float* ln1b = (const float*)d_in[11];
  const float* g2w1 = (const float*)d_in[12];
  const float* g2b1 = (const float*)d_in[13];
  const float* g2w2 = (const float*)d_in[14];
  const float* g2b2 = (const float*)d_in[15];
  const float* g2w3 = (const float*)d_in[16];
  const float* g2b3 = (const float*)d_in[17];
  const float* ln2g = (const float*)d_in[18];
  const float* ln2b = (const float*)d_in[19];
  const float* aw1 = (const float*)d_in[20];
  const float* ab1 = (const float*)d_in[21];
  const float* aw2 = (const float*)d_in[22];
  const float* ab2 = (const float*)d_in[23];
  const float* ow1 = (const float*)d_in[24];
  const float* ob1 = (const float*)d_in[25];
  const float* ow2 = (const float*)d_in[26];
  const float* ob2 = (const float*)d_in[27];
  const int* srcI = ei;        // edge_index[0] = src
  const int* dstI = ei + NE;   // edge_index[1] = dst

  char* wp = (char*)d_ws;
  size_t off = 0;
  auto alloc = [&](size_t bytes) {
    void* p = wp + off;
    off += (bytes + 255) & ~(size_t)255;
    return p;
  };
  unsigned short* W1catT = (unsigned short*)alloc((size_t)512 * 64 * 2);
  unsigned short* W2catT = (unsigned short*)alloc((size_t)512 * 256 * 2);
  unsigned short* g1w2T = (unsigned short*)alloc((size_t)256 * 256 * 2);
  unsigned short* g1w3T = (unsigned short*)alloc((size_t)256 * 256 * 2);
  unsigned short* g2w2T = (unsigned short*)alloc((size_t)256 * 256 * 2);
  unsigned short* g2w3T = (unsigned short*)alloc((size_t)256 * 256 * 2);
  unsigned short* aw1T = (unsigned short*)alloc((size_t)256 * 256 * 2);
  unsigned short* aw2T = (unsigned short*)alloc((size_t)32 * 256 * 2);
  unsigned short* ow1T = (unsigned short*)alloc((size_t)256 * 256 * 2);
  unsigned short* ow2T = (unsigned short*)alloc((size_t)128 * 256 * 2);
  unsigned short* xb = (unsigned short*)alloc((size_t)NN * 64 * 2);
  unsigned short* PQ = (unsigned short*)alloc((size_t)NN * 512 * 2);
  float* agg = (float*)alloc((size_t)NN * 256 * 4);
  unsigned short* x1b = (unsigned short*)alloc((size_t)NN * 256 * 2);
  unsigned short* x2b = (unsigned short*)alloc((size_t)NN * 256 * 2);
  unsigned short* assh = (unsigned short*)alloc((size_t)NN * 256 * 2);
  float* logits = (float*)alloc((size_t)NN * 32 * 4);
  float* pooled = (float*)alloc((size_t)512 * 256 * 4);
  unsigned short* pooledb = (unsigned short*)alloc((size_t)512 * 256 * 2);
  unsigned short* hidB = (unsigned short*)alloc((size_t)512 * 256 * 2);
  int* bstart = (int*)alloc(32 * 4);
  float* accs = (float*)alloc(64 * 4);
  int* deg = (int*)alloc((size_t)NN * 4);
  int* cursor = (int*)alloc((size_t)NN * 4);
  int* rowstart = (int*)alloc((size_t)(NN + 1) * 4);
  int* sSrc = (int*)alloc((size_t)NE * 4);
  int* sDst = (int*)alloc((size_t)NE * 4);
  unsigned short* m = (unsigned short*)alloc((size_t)NE * 256 * 2);  // 164 MB
  const bool fast = (ws_size >= off);

  float* out_f = (float*)d_out;
  float* out_latent = out_f;                 // [16*32*128] = 65536
  float* out_s = out_f + 65536;              // [20000*32]
  float* out_loss = out_f + 65536 + 640000;  // [1]

  TDs tds;
  tds.t[0] = {g1w1, W1catT, 64, 256, 0, 256};
  tds.t[1] = {g1w1, W1catT + 256 * 64, 64, 256, 64, 256};
  tds.t[2] = {g1w2, g1w2T, 256, 256, 0, 256};
  tds.t[3] = {g1w3, g1w3T, 256, 256, 0, 256};
  tds.t[4] = {g2w1, W2catT, 256, 256, 0, 256};
  tds.t[5] = {g2w1, W2catT + 256 * 256, 256, 256, 256, 256};
  tds.t[6] = {g2w2, g2w2T, 256, 256, 0, 256};
  tds.t[7] = {g2w3, g2w3T, 256, 256, 0, 256};
  tds.t[8] = {aw1, aw1T, 256, 256, 0, 256};
  tds.t[9] = {aw2, aw2T, 256, 32, 0, 32};
  tds.t[10] = {ow1, ow1T, 256, 256, 0, 256};
  tds.t[11] = {ow2, ow2T, 256, 128, 0, 128};
  tds.t[12] = {x, xb, NN * 64, 1, 0, 0};

  wprep<<<dim3(128, 13), 256, 0, stream>>>(tds);
  (void)hipMemsetAsync(accs, 0, 64 * 4, stream);
  (void)hipMemsetAsync(pooled, 0, (size_t)512 * 256 * 4, stream);

  if (fast) {
    // CSR build (dst-sorted edges)
    (void)hipMemsetAsync(deg, 0, (size_t)NN * 4, stream);
    hist_kernel<<<dim3(1250), 256, 0, stream>>>(dstI, deg);
    scan_deg<<<dim3(1), 256, 0, stream>>>(deg, rowstart, cursor);
    fillcsr<<<dim3(1250), 256, 0, stream>>>(srcI, dstI, cursor, sSrc, sDst);

    // layer 1
    gemmT<0><<<dim3(2, 157), 512, 0, stream>>>(W1catT, xb, nullptr, PQ, NN, 64, 512, 512);
    edge_mlp_sorted<<<dim3(2500), 512, 0, stream>>>(PQ, sSrc, sDst, g1b1, g1w2T, g1b2, g1w3T, m);
    agg_ln<<<dim3(5000), 256, 0, stream>>>(m, rowstart, g1b3, ln1g, ln1b, x1b);
    // layer 2
    gemmT<0><<<dim3(2, 157), 512, 0, stream>>>(W2catT, x1b, nullptr, PQ, NN, 256, 512, 512);
    edge_mlp_sorted<<<dim3(2500), 512, 0, stream>>>(PQ, sSrc, sDst, g2b1, g2w2T, g2b2, g2w3T, m);
    agg_ln<<<dim3(5000), 256, 0, stream>>>(m, rowstart, g2b3, ln2g, ln2b, x2b);
  } else {
    // fallback (atomic scatter) — validated round-4 path
    (void)hipMemsetAsync(agg, 0, (size_t)NN * 256 * 4, stream);
    gemmT<0><<<dim3(2, 157), 512, 0, stream>>>(W1catT, xb, nullptr, PQ, NN, 64, 512, 512);
    edge_mlp_atomic<<<dim3(2500), 512, 0, stream>>>(PQ, srcI, dstI, g1b1, g1w2T, g1b2, g1w3T, g1b3, agg);
    relu_ln<<<dim3(5000), 256, 0, stream>>>(agg, ln1g, ln1b, x1b);
    (void)hipMemsetAsync(agg, 0, (size_t)NN * 256 * 4, stream);
    gemmT<0><<<dim3(2, 157), 512, 0, stream>>>(W2catT, x1b, nullptr, PQ, NN, 256, 512, 512);
    edge_mlp_atomic<<<dim3(2500), 512, 0, stream>>>(PQ, srcI, dstI, g2b1, g2w2T, g2b2, g2w3T, g2b3, agg);
    relu_ln<<<dim3(5000), 256, 0, stream>>>(agg, ln2g, ln2b, x2b);
  }

  // assignment MLP + gumbel softmax (s written fp32 directly to d_out)
  gemmT<1><<<dim3(1, 157), 512, 0, stream>>>(aw1T, x2b, ab1, assh, NN, 256, 256, 256);
  gemmT<2><<<dim3(1, 157), 512, 0, stream>>>(aw2T, assh, ab2, logits, NN, 256, 32, 32);
  gumbel_softmax<<<dim3(79), 256, 0, stream>>>(logits, u, out_s, accs, accs + 16);

  // pooling + output MLP (latent fp32 to d_out)
  find_bounds<<<dim3(79), 256, 0, stream>>>(batch, bstart);
  pool_kernel<<<dim3(16, 12), 256, 0, stream>>>(x2b, out_s, bstart, pooled);
  cast_kernel<<<dim3(512), 256, 0, stream>>>(pooled, pooledb, 512 * 256);
  gemmT<1><<<dim3(1, 4), 512, 0, stream>>>(ow1T, pooledb, ob1, hidB, 512, 256, 256, 256);
  gemmT<2><<<dim3(1, 4), 512, 0, stream>>>(ow2T, hidB, ob2, out_latent, 512, 256, 128, 128);
  loss_kernel<<<dim3(1), 64, 0, stream>>>(accs, out_loss);
}

// Round 6
// 996.096 us; speedup vs baseline: 2.7007x; 1.1637x over previous
//
#include <hip/hip_runtime.h>
#include <stdint.h>

#define NN 20000      // nodes
#define NE 320000     // edges
#define NBATCH 16

typedef short short8 __attribute__((ext_vector_type(8)));   // 8 x bf16 bits (4 VGPR)
typedef float f32x4  __attribute__((ext_vector_type(4)));   // MFMA acc

__device__ __forceinline__ unsigned short f2bf(float f) {
  union { float f; unsigned u; } v; v.f = f;
  unsigned r = v.u + 0x7FFFu + ((v.u >> 16) & 1u);   // RNE
  return (unsigned short)(r >> 16);
}
__device__ __forceinline__ float bf2f(unsigned short h) {
  union { unsigned u; float f; } v; v.u = ((unsigned)h) << 16;
  return v.f;
}
__device__ __forceinline__ float bf2fs(short h) { return bf2f((unsigned short)h); }

// LDS tile: 128 edges x 256 bf16, XOR-swizzled 16B granules, exactly 64 KB.
#define HOFF(e, k) (((e) << 8) + (((((k) >> 3) ^ ((e) & 7)) << 3) + ((k) & 7)))

// ---------------- weight prep: fp32 [K,N] -> bf16 transposed [N,K] (or plain cast) ----------------
struct TD { const float* s; unsigned short* d; int R, C, r0, ld; };
struct TDs { TD t[13]; };

__global__ void wprep(TDs all) {
  TD td = all.t[blockIdx.y];
  int stride = gridDim.x * blockDim.x;
  int i0 = blockIdx.x * blockDim.x + threadIdx.x;
  if (td.ld == 0) {                       // plain cast copy
    for (int i = i0; i < td.R; i += stride) td.d[i] = f2bf(td.s[i]);
  } else {                                // dst[c*R + r] = src[(r0+r)*ld + c]
    int total = td.R * td.C;
    for (int i = i0; i < total; i += stride) {
      int c = i / td.R;
      int r = i - c * td.R;
      td.d[i] = f2bf(td.s[(size_t)(td.r0 + r) * td.ld + c]);
    }
  }
}

// ---------------- CSR build (dst-sorted edge permutation) ----------------
__global__ void hist_kernel(const int* __restrict__ dstI, int* __restrict__ deg) {
  int e = blockIdx.x * 256 + threadIdx.x;
  if (e < NE) atomicAdd(&deg[dstI[e]], 1);
}

// block 0: exclusive scan of deg -> rowstart/cursor; blocks 1..79: batch segment bounds
__global__ void scan_bounds(const int* __restrict__ deg, int* __restrict__ rowstart,
                            int* __restrict__ cursor, const int* __restrict__ batch,
                            int* __restrict__ bstart) {
  if (blockIdx.x == 0) {
    __shared__ int part[256];
    int t = threadIdx.x;
    int c0 = t * 80; if (c0 > NN) c0 = NN;
    int c1 = c0 + 80; if (c1 > NN) c1 = NN;
    int s = 0;
    for (int i = c0; i < c1; ++i) s += deg[i];
    part[t] = s;
    __syncthreads();
    if (t == 0) {
      int run = 0;
      for (int i = 0; i < 256; ++i) { int v = part[i]; part[i] = run; run += v; }
    }
    __syncthreads();
    int run = part[t];
    for (int i = c0; i < c1; ++i) { rowstart[i] = run; cursor[i] = run; run += deg[i]; }
    if (t == 255) rowstart[NN] = run;   // == NE
  } else {
    int n = (blockIdx.x - 1) * 256 + threadIdx.x;
    if (n >= NN) return;
    int bn = batch[n];
    if (n == 0) {
      for (int b2 = 0; b2 <= bn; ++b2) bstart[b2] = 0;
    } else {
      int bp = batch[n - 1];
      for (int b2 = bp + 1; b2 <= bn; ++b2) bstart[b2] = n;
    }
    if (n == NN - 1) {
      for (int b2 = bn + 1; b2 <= NBATCH; ++b2) bstart[b2] = NN;
    }
  }
}

__global__ void fillcsr(const int* __restrict__ srcI, const int* __restrict__ dstI,
                        int* __restrict__ cursor, int* __restrict__ sSrc,
                        int* __restrict__ sDst) {
  int e = blockIdx.x * 256 + threadIdx.x;
  if (e < NE) {
    int d = dstI[e];
    int slot = atomicAdd(&cursor[d], 1);
    sDst[slot] = d;
    sSrc[slot] = srcI[e];
  }
}

// ---------------- generic transposed-weight GEMM: Out[r][f] = In[r][:] . WT[f][:] ----------------
template <int EPI>  // 0: bf16 store (+bias), 1: bf16 relu(+bias), 2: f32 store (+bias)
__global__ __launch_bounds__(512, 4) void gemmT(
    const unsigned short* __restrict__ WT, const unsigned short* __restrict__ In,
    const float* __restrict__ bias, void* __restrict__ Out,
    int M, int K, int Nout, int ldo) {
  const int tid = threadIdx.x;
  const int lane = tid & 63, w = tid >> 6;
  const int wf = w >> 1, we = w & 1;
  const int l15 = lane & 15, q = lane >> 4;
  const int fb = blockIdx.x * 256 + wf * 64;
  const int rb = blockIdx.y * 128 + we * 64;
  f32x4 acc[4][4] = {};
  const short8 zz = {0, 0, 0, 0, 0, 0, 0, 0};
  for (int kc = 0; kc < K; kc += 32) {
    short8 a[4], bq[4];
#pragma unroll
    for (int i = 0; i < 4; ++i) {
      if (fb + i * 16 < Nout)
        a[i] = *(const short8*)(WT + (size_t)(fb + i * 16 + l15) * K + kc + q * 8);
      else
        a[i] = zz;
      int r = rb + i * 16 + l15;
      if (r >= M) r = M - 1;  // clamp: stores guarded below
      bq[i] = *(const short8*)(In + (size_t)r * K + kc + q * 8);
    }
#pragma unroll
    for (int i = 0; i < 4; ++i)
#pragma unroll
      for (int j = 0; j < 4; ++j)
        acc[i][j] = __builtin_amdgcn_mfma_f32_16x16x32_bf16(a[i], bq[j], acc[i][j], 0, 0, 0);
  }
#pragma unroll
  for (int i = 0; i < 4; ++i) {
    int f0 = fb + i * 16 + q * 4;
    if (f0 >= Nout) continue;
    float4 bs = make_float4(0.f, 0.f, 0.f, 0.f);
    if (bias) bs = *(const float4*)(bias + f0);
#pragma unroll
    for (int j = 0; j < 4; ++j) {
      int r = rb + j * 16 + l15;
      if (r >= M) continue;
      float v0 = acc[i][j][0] + bs.x;
      float v1 = acc[i][j][1] + bs.y;
      float v2 = acc[i][j][2] + bs.z;
      float v3 = acc[i][j][3] + bs.w;
      if (EPI == 1) {
        v0 = fmaxf(v0, 0.f); v1 = fmaxf(v1, 0.f); v2 = fmaxf(v2, 0.f); v3 = fmaxf(v3, 0.f);
      }
      if (EPI == 2) {
        *(float4*)((float*)Out + (size_t)r * ldo + f0) = make_float4(v0, v1, v2, v3);
      } else {
        ushort4 o;
        o.x = f2bf(v0); o.y = f2bf(v1); o.z = f2bf(v2); o.w = f2bf(v3);
        *(ushort4*)((unsigned short*)Out + (size_t)r * ldo + f0) = o;
      }
    }
  }
}

// ---------------- fused per-edge MLP + dst-segmented aggregation (no m round-trip) ----------------
// h1 = relu(PQ[sDst][0:256] + PQ[sSrc][256:512] + b1)   (LDS, 128 sorted edges)
// h2 = relu(h1 @ W2 + b2)                                (LDS, overwrite)
// m  = h2 @ W3 (bf16, LDS); segmented sum over dst runs  -> agg (+run_len*b3)
// interior runs: plain float4 store; tile-boundary runs: fp32 atomicAdd (~2/tile)
__global__ __launch_bounds__(512, 4) void edge_mlp_fused(
    const unsigned short* __restrict__ PQ, const int* __restrict__ sSrc,
    const int* __restrict__ sDst, const float* __restrict__ b1,
    const unsigned short* __restrict__ W2T, const float* __restrict__ b2,
    const unsigned short* __restrict__ W3T, const float* __restrict__ b3,
    int* __restrict__ segcnt, int* __restrict__ segbuf, float* __restrict__ agg) {
  __shared__ __align__(16) unsigned short h[128 * 256];  // exactly 64 KB -> 2 blocks/CU
  const int tid = threadIdx.x;
  const int e0 = blockIdx.x * 128;

  {  // phase 0: gather + h1.  mapping r=tid&127,chunk=tid>>7: conflict-free LDS writes,
     // 8 consecutive lanes hit 8 distinct bank groups; sorted dst rows broadcast in VMEM.
    int r = tid & 127;
    int c0 = (tid >> 7) * 64;
    int dn = sDst[e0 + r];
    int sn = sSrc[e0 + r];
    const unsigned short* pd = PQ + (size_t)dn * 512 + c0;
    const unsigned short* ps = PQ + (size_t)sn * 512 + 256 + c0;
    const float* bp = b1 + c0;
#pragma unroll
    for (int i = 0; i < 8; ++i) {
      short8 dv = *(const short8*)(pd + i * 8);
      short8 sv = *(const short8*)(ps + i * 8);
      float4 bA = *(const float4*)(bp + i * 8);
      float4 bB = *(const float4*)(bp + i * 8 + 4);
      float bb[8] = {bA.x, bA.y, bA.z, bA.w, bB.x, bB.y, bB.z, bB.w};
      short8 o;
#pragma unroll
      for (int j = 0; j < 8; ++j) {
        float v = bf2fs(dv[j]) + bf2fs(sv[j]) + bb[j];
        o[j] = (short)f2bf(fmaxf(v, 0.f));
      }
      *(short8*)&h[HOFF(r, c0 + i * 8)] = o;
    }
  }
  __syncthreads();

  const int lane = tid & 63, w = tid >> 6;
  const int wf = w >> 1, we = w & 1;
  const int l15 = lane & 15, q = lane >> 4;
  const int fb = wf * 64, eb = we * 64;
  f32x4 acc[4][4];

  // ---- GEMM1: h2^T = W2T @ h1^T ----
#pragma unroll
  for (int i = 0; i < 4; ++i)
#pragma unroll
    for (int j = 0; j < 4; ++j) { f32x4 z = {0.f, 0.f, 0.f, 0.f}; acc[i][j] = z; }
  for (int kc = 0; kc < 256; kc += 32) {
    short8 a[4], bq[4];
#pragma unroll
    for (int i = 0; i < 4; ++i)
      a[i] = *(const short8*)(W2T + (size_t)(fb + i * 16 + l15) * 256 + kc + q * 8);
#pragma unroll
    for (int j = 0; j < 4; ++j)
      bq[j] = *(const short8*)&h[HOFF(eb + j * 16 + l15, kc + q * 8)];
#pragma unroll
    for (int i = 0; i < 4; ++i)
#pragma unroll
      for (int j = 0; j < 4; ++j)
        acc[i][j] = __builtin_amdgcn_mfma_f32_16x16x32_bf16(a[i], bq[j], acc[i][j], 0, 0, 0);
  }
  __syncthreads();  // all reads of h1 done
#pragma unroll
  for (int i = 0; i < 4; ++i) {
    int f0 = fb + i * 16 + q * 4;
    float4 bs = *(const float4*)(b2 + f0);
#pragma unroll
    for (int j = 0; j < 4; ++j) {
      int e = eb + j * 16 + l15;
      ushort4 o;
      o.x = f2bf(fmaxf(acc[i][j][0] + bs.x, 0.f));
      o.y = f2bf(fmaxf(acc[i][j][1] + bs.y, 0.f));
      o.z = f2bf(fmaxf(acc[i][j][2] + bs.z, 0.f));
      o.w = f2bf(fmaxf(acc[i][j][3] + bs.w, 0.f));
      *(ushort4*)&h[HOFF(e, f0)] = o;  // h now holds h2 [edge][feat]
    }
  }
  __syncthreads();

  // ---- GEMM2: m^T = W3T @ h2^T ----
#pragma unroll
  for (int i = 0; i < 4; ++i)
#pragma unroll
    for (int j = 0; j < 4; ++j) { f32x4 z = {0.f, 0.f, 0.f, 0.f}; acc[i][j] = z; }
  for (int kc = 0; kc < 256; kc += 32) {
    short8 a[4], bq[4];
#pragma unroll
    for (int i = 0; i < 4; ++i)
      a[i] = *(const short8*)(W3T + (size_t)(fb + i * 16 + l15) * 256 + kc + q * 8);
#pragma unroll
    for (int j = 0; j < 4; ++j)
      bq[j] = *(const short8*)&h[HOFF(eb + j * 16 + l15, kc + q * 8)];
#pragma unroll
    for (int i = 0; i < 4; ++i)
#pragma unroll
      for (int j = 0; j < 4; ++j)
        acc[i][j] = __builtin_amdgcn_mfma_f32_16x16x32_bf16(a[i], bq[j], acc[i][j], 0, 0, 0);
  }
  __syncthreads();  // all reads of h2 done before overwrite

  // write m (bf16, b3 deferred) into h; find segment starts (global scratch, LDS stays 64 KB)
#pragma unroll
  for (int i = 0; i < 4; ++i) {
    int f0 = fb + i * 16 + q * 4;
#pragma unroll
    for (int j = 0; j < 4; ++j) {
      int e = eb + j * 16 + l15;
      ushort4 o;
      o.x = f2bf(acc[i][j][0]); o.y = f2bf(acc[i][j][1]);
      o.z = f2bf(acc[i][j][2]); o.w = f2bf(acc[i][j][3]);
      *(ushort4*)&h[HOFF(e, f0)] = o;  // h now holds m [edge][feat]
    }
  }
  if (tid < 128) {
    int d0 = sDst[e0 + tid];
    bool flag = (tid == 0) || (sDst[e0 + tid - 1] != d0);
    if (flag) {
      int idx = atomicAdd(&segcnt[blockIdx.x], 1);
      segbuf[blockIdx.x * 128 + idx] = tid;
    }
  }
  __syncthreads();

  // segmented reduction: group sg (8 groups x 64 lanes, 4 feats/lane) sums runs in fp32
  {
    int cnt = segcnt[blockIdx.x];
    int f4 = (tid & 63) * 4;
    int sg = tid >> 6;
    const int* sb = segbuf + blockIdx.x * 128;
    float4 b3v = *(const float4*)(b3 + f4);
    for (int k = sg; k < cnt; k += 8) {
      int start = sb[k];
      int end = 128;
      for (int j2 = 0; j2 < cnt; ++j2) {
        int v = sb[j2];
        if (v > start && v < end) end = v;
      }
      int node = sDst[e0 + start];
      float s0 = 0.f, s1 = 0.f, s2 = 0.f, s3 = 0.f;
      for (int r = start; r < end; ++r) {
        ushort4 v = *(const ushort4*)&h[HOFF(r, f4)];
        s0 += bf2f(v.x); s1 += bf2f(v.y); s2 += bf2f(v.z); s3 += bf2f(v.w);
      }
      float c = (float)(end - start);
      s0 += c * b3v.x; s1 += c * b3v.y; s2 += c * b3v.z; s3 += c * b3v.w;
      float* pr = agg + (size_t)node * 256 + f4;
      if (start == 0 || end == 128) {  // run may continue in neighbor tile
        atomicAdd(pr + 0, s0); atomicAdd(pr + 1, s1);
        atomicAdd(pr + 2, s2); atomicAdd(pr + 3, s3);
      } else {                         // run wholly inside this tile: unique owner
        *(float4*)pr = make_float4(s0, s1, s2, s3);
      }
    }
  }
}

// ---------------- fallback: fused per-edge MLP with atomic scatter (round-4 path) ----------------
__global__ __launch_bounds__(512, 4) void edge_mlp_atomic(
    const unsigned short* __restrict__ PQ, const int* __restrict__ srcI,
    const int* __restrict__ dstI, const float* __restrict__ b1,
    const unsigned short* __restrict__ W2T, const float* __restrict__ b2,
    const unsigned short* __restrict__ W3T, const float* __restrict__ b3,
    float* __restrict__ agg) {
  __shared__ __align__(16) unsigned short h[128 * 256];
  const int tid = threadIdx.x;
  const int e0 = blockIdx.x * 128;
  {
    int r = tid & 127;
    int c0 = (tid >> 7) * 64;
    int dn = dstI[e0 + r];
    int sn = srcI[e0 + r];
    const unsigned short* pd = PQ + (size_t)dn * 512 + c0;
    const unsigned short* ps = PQ + (size_t)sn * 512 + 256 + c0;
    const float* bp = b1 + c0;
#pragma unroll
    for (int i = 0; i < 8; ++i) {
      short8 dv = *(const short8*)(pd + i * 8);
      short8 sv = *(const short8*)(ps + i * 8);
      float4 bA = *(const float4*)(bp + i * 8);
      float4 bB = *(const float4*)(bp + i * 8 + 4);
      float bb[8] = {bA.x, bA.y, bA.z, bA.w, bB.x, bB.y, bB.z, bB.w};
      short8 o;
#pragma unroll
      for (int j = 0; j < 8; ++j) {
        float v = bf2fs(dv[j]) + bf2fs(sv[j]) + bb[j];
        o[j] = (short)f2bf(fmaxf(v, 0.f));
      }
      *(short8*)&h[HOFF(r, c0 + i * 8)] = o;
    }
  }
  __syncthreads();
  const int lane = tid & 63, w = tid >> 6;
  const int wf = w >> 1, we = w & 1;
  const int l15 = lane & 15, q = lane >> 4;
  const int fb = wf * 64, eb = we * 64;
  f32x4 acc[4][4];
#pragma unroll
  for (int i = 0; i < 4; ++i)
#pragma unroll
    for (int j = 0; j < 4; ++j) { f32x4 z = {0.f, 0.f, 0.f, 0.f}; acc[i][j] = z; }
  for (int kc = 0; kc < 256; kc += 32) {
    short8 a[4], bq[4];
#pragma unroll
    for (int i = 0; i < 4; ++i)
      a[i] = *(const short8*)(W2T + (size_t)(fb + i * 16 + l15) * 256 + kc + q * 8);
#pragma unroll
    for (int j = 0; j < 4; ++j)
      bq[j] = *(const short8*)&h[HOFF(eb + j * 16 + l15, kc + q * 8)];
#pragma unroll
    for (int i = 0; i < 4; ++i)
#pragma unroll
      for (int j = 0; j < 4; ++j)
        acc[i][j] = __builtin_amdgcn_mfma_f32_16x16x32_bf16(a[i], bq[j], acc[i][j], 0, 0, 0);
  }
  __syncthreads();
#pragma unroll
  for (int i = 0; i < 4; ++i) {
    int f0 = fb + i * 16 + q * 4;
    float4 bs = *(const float4*)(b2 + f0);
#pragma unroll
    for (int j = 0; j < 4; ++j) {
      int e = eb + j * 16 + l15;
      ushort4 o;
      o.x = f2bf(fmaxf(acc[i][j][0] + bs.x, 0.f));
      o.y = f2bf(fmaxf(acc[i][j][1] + bs.y, 0.f));
      o.z = f2bf(fmaxf(acc[i][j][2] + bs.z, 0.f));
      o.w = f2bf(fmaxf(acc[i][j][3] + bs.w, 0.f));
      *(ushort4*)&h[HOFF(e, f0)] = o;
    }
  }
  __syncthreads();
#pragma unroll
  for (int i = 0; i < 4; ++i)
#pragma unroll
    for (int j = 0; j < 4; ++j) { f32x4 z = {0.f, 0.f, 0.f, 0.f}; acc[i][j] = z; }
  for (int kc = 0; kc < 256; kc += 32) {
    short8 a[4], bq[4];
#pragma unroll
    for (int i = 0; i < 4; ++i)
      a[i] = *(const short8*)(W3T + (size_t)(fb + i * 16 + l15) * 256 + kc + q * 8);
#pragma unroll
    for (int j = 0; j < 4; ++j)
      bq[j] = *(const short8*)&h[HOFF(eb + j * 16 + l15, kc + q * 8)];
#pragma unroll
    for (int i = 0; i < 4; ++i)
#pragma unroll
      for (int j = 0; j < 4; ++j)
        acc[i][j] = __builtin_amdgcn_mfma_f32_16x16x32_bf16(a[i], bq[j], acc[i][j], 0, 0, 0);
  }
#pragma unroll
  for (int j = 0; j < 4; ++j) {
    int eg = e0 + eb + j * 16 + l15;
    int dn = dstI[eg];
    float* pr = agg + (size_t)dn * 256;
#pragma unroll
    for (int i = 0; i < 4; ++i) {
      int f0 = fb + i * 16 + q * 4;
      float4 bs = *(const float4*)(b3 + f0);
      atomicAdd(pr + f0 + 0, acc[i][j][0] + bs.x);
      atomicAdd(pr + f0 + 1, acc[i][j][1] + bs.y);
      atomicAdd(pr + f0 + 2, acc[i][j][2] + bs.z);
      atomicAdd(pr + f0 + 3, acc[i][j][3] + bs.w);
    }
  }
}

// ---------------- relu + layernorm, fp32 in -> bf16 out ----------------
__global__ void relu_ln(const float* __restrict__ agg, const float* __restrict__ g,
                        const float* __restrict__ b, unsigned short* __restrict__ out) {
  int row = blockIdx.x * 4 + (threadIdx.x >> 6);
  int lane = threadIdx.x & 63;
  if (row >= NN) return;
  float4 v = *(const float4*)(agg + (size_t)row * 256 + lane * 4);
  v.x = fmaxf(v.x, 0.f); v.y = fmaxf(v.y, 0.f); v.z = fmaxf(v.z, 0.f); v.w = fmaxf(v.w, 0.f);
  float s = v.x + v.y + v.z + v.w;
  float sq = v.x * v.x + v.y * v.y + v.z * v.z + v.w * v.w;
  for (int off = 32; off >= 1; off >>= 1) {
    s += __shfl_xor(s, off);
    sq += __shfl_xor(sq, off);
  }
  float mu = s * (1.f / 256.f);
  float var = sq * (1.f / 256.f) - mu * mu;
  float rs = rsqrtf(var + 1e-5f);
  float4 gg = *(const float4*)(g + lane * 4);
  float4 bb = *(const float4*)(b + lane * 4);
  ushort4 o;
  o.x = f2bf((v.x - mu) * rs * gg.x + bb.x);
  o.y = f2bf((v.y - mu) * rs * gg.y + bb.y);
  o.z = f2bf((v.z - mu) * rs * gg.z + bb.z);
  o.w = f2bf((v.w - mu) * rs * gg.w + bb.w);
  *(ushort4*)(out + (size_t)row * 256 + lane * 4) = o;
}

// ---------------- gumbel softmax + entropy/avg_s accumulation; s written fp32 to d_out ----------------
__global__ void gumbel_softmax(const float* __restrict__ logits, const float* __restrict__ u,
                               float* __restrict__ sf,
                               float* __restrict__ entacc, float* __restrict__ avgacc) {
  __shared__ float lavg[32];
  __shared__ float lent;
  int t = threadIdx.x;
  if (t < 32) lavg[t] = 0.f;
  if (t == 0) lent = 0.f;
  __syncthreads();
  int n = blockIdx.x * 256 + t;
  if (n < NN) {
    float z[32];
    float m = -1e30f;
#pragma unroll
    for (int k = 0; k < 8; ++k) {
      float4 lg = *(const float4*)(logits + (size_t)n * 32 + k * 4);
      float4 uu = *(const float4*)(u + (size_t)n * 32 + k * 4);
      float a0 = lg.x - logf(-logf(uu.x + 1e-9f) + 1e-9f);
      float a1 = lg.y - logf(-logf(uu.y + 1e-9f) + 1e-9f);
      float a2 = lg.z - logf(-logf(uu.z + 1e-9f) + 1e-9f);
      float a3 = lg.w - logf(-logf(uu.w + 1e-9f) + 1e-9f);
      z[k * 4 + 0] = a0; z[k * 4 + 1] = a1; z[k * 4 + 2] = a2; z[k * 4 + 3] = a3;
      m = fmaxf(m, fmaxf(fmaxf(a0, a1), fmaxf(a2, a3)));
    }
    float sum = 0.f;
#pragma unroll
    for (int j = 0; j < 32; ++j) { z[j] = expf(z[j] - m); sum += z[j]; }
    float inv = 1.f / sum;
    float ent = 0.f;
#pragma unroll
    for (int j = 0; j < 32; ++j) {
      float sj = z[j] * inv;
      sf[(size_t)n * 32 + j] = sj;
      ent += sj * logf(sj + 1e-9f);
      atomicAdd(&lavg[j], sj);
    }
    atomicAdd(&lent, ent);
  }
  __syncthreads();
  if (t < 32) atomicAdd(&avgacc[t], lavg[t]);
  if (t == 0) atomicAdd(entacc, lent);
}

// ---------------- batch segment bounds (standalone, fallback path) ----------------
__global__ void find_bounds(const int* __restrict__ batch, int* __restrict__ bstart) {
  int n = blockIdx.x * 256 + threadIdx.x;
  if (n >= NN) return;
  int bn = batch[n];
  if (n == 0) {
    for (int b2 = 0; b2 <= bn; ++b2) bstart[b2] = 0;
  } else {
    int bp = batch[n - 1];
    for (int b2 = bp + 1; b2 <= bn; ++b2) bstart[b2] = n;
  }
  if (n == NN - 1) {
    for (int b2 = bn + 1; b2 <= NBATCH; ++b2) bstart[b2] = NN;
  }
}

// ---------------- pooled[b,s,h] = sum_n x2[n,h]*s[n,s] ----------------
__global__ void pool_kernel(const unsigned short* __restrict__ x2b, const float* __restrict__ sf,
                            const int* __restrict__ bstart, float* __restrict__ pooled) {
  int b = blockIdx.x, ci = blockIdx.y;
  int n0b = bstart[b], n1b = bstart[b + 1];
  int t = threadIdx.x;
  int si = t >> 3;          // 0..31
  int hb = (t & 7) * 32;    // 0..224
  float acc[32];
#pragma unroll
  for (int k = 0; k < 32; ++k) acc[k] = 0.f;
  for (int nst = n0b + ci * 128; nst < n1b; nst += gridDim.y * 128) {
    int nend = (nst + 128 < n1b) ? nst + 128 : n1b;
    for (int n = nst; n < nend; ++n) {
      float sv = sf[(size_t)n * 32 + si];
      const unsigned short* xr = x2b + (size_t)n * 256 + hb;
#pragma unroll
      for (int k2 = 0; k2 < 4; ++k2) {
        short8 xv = *(const short8*)(xr + k2 * 8);
#pragma unroll
        for (int jj = 0; jj < 8; ++jj) acc[k2 * 8 + jj] = fmaf(sv, bf2fs(xv[jj]), acc[k2 * 8 + jj]);
      }
    }
  }
  float* pp = pooled + (size_t)(b * 32 + si) * 256 + hb;
#pragma unroll
  for (int k = 0; k < 32; ++k) atomicAdd(pp + k, acc[k]);
}

__global__ void cast_kernel(const float* __restrict__ in, unsigned short* __restrict__ out, int n) {
  int i = blockIdx.x * 256 + threadIdx.x;
  if (i < n) out[i] = f2bf(in[i]);
}

__global__ void loss_kernel(const float* __restrict__ accs, float* __restrict__ outloss) {
  int t = threadIdx.x;
  float d = 0.f;
  if (t < 32) {
    float a = accs[16 + t] * (1.f / NN);
    d = a * logf(a + 1e-9f);
  }
  for (int off = 32; off >= 1; off >>= 1) d += __shfl_xor(d, off);
  if (t == 0) {
    float ent = -accs[0] * (1.f / NN);
    outloss[0] = ent + d;
  }
}

// ---------------- orchestration ----------------
extern "C" void kernel_launch(void* const* d_in, const int* in_sizes, int n_in,
                              void* d_out, int out_size, void* d_ws, size_t ws_size,
                              hipStream_t stream) {
  (void)in_sizes; (void)n_in; (void)out_size;
  const float* x = (const float*)d_in[0];
  const float* u = (const float*)d_in[1];
  const int* ei = (const int*)d_in[2];
  const int* batch = (const int*)d_in[3];
  const float* g1w1 = (const float*)d_in[4];
  const float* g1b1 = (const float*)d_in[5];
  const float* g1w2 = (const float*)d_in[6];
  const float* g1b2 = (const float*)d_in[7];
  const float* g1w3 = (const float*)d_in[8];
  const float* g1b3 = (const float*)d_in[9];
  const float* ln1g = (const float*)d_in[10];
  const float* ln1b = (const float*)d_in[11];
  const float* g2w1 = (const float*)d_in[12];
  const float* g2b1 = (const float*)d_in[13];
  const float* g2w2 = (const float*)d_in[14];
  const float* g2b2 = (const float*)d_in[15];
  const float* g2w3 = (const float*)d_in[16];
  const float* g2b3 = (const float*)d_in[17];
  const float* ln2g = (const float*)d_in[18];
  const float* ln2b = (const float*)d_in[19];
  const float* aw1 = (const float*)d_in[20];
  const float* ab1 = (const float*)d_in[21];
  const float* aw2 = (const float*)d_in[22];
  const float* ab2 = (const float*)d_in[23];
  const float* ow1 = (const float*)d_in[24];
  const float* ob1 = (const float*)d_in[25];
  const float* ow2 = (const float*)d_in[26];
  const float* ob2 = (const float*)d_in[27];
  const int* srcI = ei;        // edge_index[0] = src
  const int* dstI = ei + NE;   // edge_index[1] = dst

  char* wp = (char*)d_ws;
  size_t off = 0;
  auto alloc = [&](size_t bytes) {
    void* p = wp + off;
    off += (bytes + 255) & ~(size_t)255;
    return p;
  };
  unsigned short* W1catT = (unsigned short*)alloc((size_t)512 * 64 * 2);
  unsigned short* W2catT = (unsigned short*)alloc((size_t)512 * 256 * 2);
  unsigned short* g1w2T = (unsigned short*)alloc((size_t)256 * 256 * 2);
  unsigned short* g1w3T = (unsigned short*)alloc((size_t)256 * 256 * 2);
  unsigned short* g2w2T = (unsigned short*)alloc((size_t)256 * 256 * 2);
  unsigned short* g2w3T = (unsigned short*)alloc((size_t)256 * 256 * 2);
  unsigned short* aw1T = (unsigned short*)alloc((size_t)256 * 256 * 2);
  unsigned short* aw2T = (unsigned short*)alloc((size_t)32 * 256 * 2);
  unsigned short* ow1T = (unsigned short*)alloc((size_t)256 * 256 * 2);
  unsigned short* ow2T = (unsigned short*)alloc((size_t)128 * 256 * 2);
  unsigned short* xb = (unsigned short*)alloc((size_t)NN * 64 * 2);
  unsigned short* PQ = (unsigned short*)alloc((size_t)NN * 512 * 2);
  float* agg = (float*)alloc((size_t)NN * 256 * 4);
  unsigned short* x1b = (unsigned short*)alloc((size_t)NN * 256 * 2);
  unsigned short* x2b = (unsigned short*)alloc((size_t)NN * 256 * 2);
  unsigned short* assh = (unsigned short*)alloc((size_t)NN * 256 * 2);
  float* logits = (float*)alloc((size_t)NN * 32 * 4);
  float* pooled = (float*)alloc((size_t)512 * 256 * 4);
  unsigned short* pooledb = (unsigned short*)alloc((size_t)512 * 256 * 2);
  unsigned short* hidB = (unsigned short*)alloc((size_t)512 * 256 * 2);
  int* bstart = (int*)alloc(32 * 4);
  float* accs = (float*)alloc(64 * 4);
  int* deg = (int*)alloc((size_t)NN * 4);
  int* cursor = (int*)alloc((size_t)NN * 4);
  int* rowstart = (int*)alloc((size_t)(NN + 1) * 4);
  int* sSrc = (int*)alloc((size_t)NE * 4);
  int* sDst = (int*)alloc((size_t)NE * 4);
  int* segcnt = (int*)alloc((size_t)2 * 2500 * 4);          // per-tile counts, both layers
  int* segbuf = (int*)alloc((size_t)2 * 2500 * 128 * 4);    // per-tile segment starts
  const bool fast = (ws_size >= off);

  float* out_f = (float*)d_out;
  float* out_latent = out_f;                 // [16*32*128] = 65536
  float* out_s = out_f + 65536;              // [20000*32]
  float* out_loss = out_f + 65536 + 640000;  // [1]

  TDs tds;
  tds.t[0] = {g1w1, W1catT, 64, 256, 0, 256};
  tds.t[1] = {g1w1, W1catT + 256 * 64, 64, 256, 64, 256};
  tds.t[2] = {g1w2, g1w2T, 256, 256, 0, 256};
  tds.t[3] = {g1w3, g1w3T, 256, 256, 0, 256};
  tds.t[4] = {g2w1, W2catT, 256, 256, 0, 256};
  tds.t[5] = {g2w1, W2catT + 256 * 256, 256, 256, 256, 256};
  tds.t[6] = {g2w2, g2w2T, 256, 256, 0, 256};
  tds.t[7] = {g2w3, g2w3T, 256, 256, 0, 256};
  tds.t[8] = {aw1, aw1T, 256, 256, 0, 256};
  tds.t[9] = {aw2, aw2T, 256, 32, 0, 32};
  tds.t[10] = {ow1, ow1T, 256, 256, 0, 256};
  tds.t[11] = {ow2, ow2T, 256, 128, 0, 128};
  tds.t[12] = {x, xb, NN * 64, 1, 0, 0};

  wprep<<<dim3(128, 13), 256, 0, stream>>>(tds);
  (void)hipMemsetAsync(accs, 0, 64 * 4, stream);
  (void)hipMemsetAsync(pooled, 0, (size_t)512 * 256 * 4, stream);

  if (fast) {
    // CSR build (dst-sorted edges) + batch bounds
    (void)hipMemsetAsync(deg, 0, (size_t)NN * 4, stream);
    (void)hipMemsetAsync(segcnt, 0, (size_t)2 * 2500 * 4, stream);
    hist_kernel<<<dim3(1250), 256, 0, stream>>>(dstI, deg);
    scan_bounds<<<dim3(80), 256, 0, stream>>>(deg, rowstart, cursor, batch, bstart);
    fillcsr<<<dim3(1250), 256, 0, stream>>>(srcI, dstI, cursor, sSrc, sDst);

    // layer 1
    (void)hipMemsetAsync(agg, 0, (size_t)NN * 256 * 4, stream);
    gemmT<0><<<dim3(2, 157), 512, 0, stream>>>(W1catT, xb, nullptr, PQ, NN, 64, 512, 512);
    edge_mlp_fused<<<dim3(2500), 512, 0, stream>>>(PQ, sSrc, sDst, g1b1, g1w2T, g1b2, g1w3T,
                                                   g1b3, segcnt, segbuf, agg);
    relu_ln<<<dim3(5000), 256, 0, stream>>>(agg, ln1g, ln1b, x1b);
    // layer 2
    (void)hipMemsetAsync(agg, 0, (size_t)NN * 256 * 4, stream);
    gemmT<0><<<dim3(2, 157), 512, 0, stream>>>(W2catT, x1b, nullptr, PQ, NN, 256, 512, 512);
    edge_mlp_fused<<<dim3(2500), 512, 0, stream>>>(PQ, sSrc, sDst, g2b1, g2w2T, g2b2, g2w3T,
                                                   g2b3, segcnt + 2500, segbuf + 2500 * 128, agg);
    relu_ln<<<dim3(5000), 256, 0, stream>>>(agg, ln2g, ln2b, x2b);
  } else {
    // fallback (atomic scatter) — validated round-4 path
    find_bounds<<<dim3(79), 256, 0, stream>>>(batch, bstart);
    (void)hipMemsetAsync(agg, 0, (size_t)NN * 256 * 4, stream);
    gemmT<0><<<dim3(2, 157), 512, 0, stream>>>(W1catT, xb, nullptr, PQ, NN, 64, 512, 512);
    edge_mlp_atomic<<<dim3(2500), 512, 0, stream>>>(PQ, srcI, dstI, g1b1, g1w2T, g1b2, g1w3T, g1b3, agg);
    relu_ln<<<dim3(5000), 256, 0, stream>>>(agg, ln1g, ln1b, x1b);
    (void)hipMemsetAsync(agg, 0, (size_t)NN * 256 * 4, stream);
    gemmT<0><<<dim3(2, 157), 512, 0, stream>>>(W2catT, x1b, nullptr, PQ, NN, 256, 512, 512);
    edge_mlp_atomic<<<dim3(2500), 512, 0, stream>>>(PQ, srcI, dstI, g2b1, g2w2T, g2b2, g2w3T, g2b3, agg);
    relu_ln<<<dim3(5000), 256, 0, stream>>>(agg, ln2g, ln2b, x2b);
  }

  // assignment MLP + gumbel softmax (s written fp32 directly to d_out)
  gemmT<1><<<dim3(1, 157), 512, 0, stream>>>(aw1T, x2b, ab1, assh, NN, 256, 256, 256);
  gemmT<2><<<dim3(1, 157), 512, 0, stream>>>(aw2T, assh, ab2, logits, NN, 256, 32, 32);
  gumbel_softmax<<<dim3(79), 256, 0, stream>>>(logits, u, out_s, accs, accs + 16);

  // pooling + output MLP (latent fp32 to d_out)
  pool_kernel<<<dim3(16, 12), 256, 0, stream>>>(x2b, out_s, bstart, pooled);
  cast_kernel<<<dim3(512), 256, 0, stream>>>(pooled, pooledb, 512 * 256);
  gemmT<1><<<dim3(1, 4), 512, 0, stream>>>(ow1T, pooledb, ob1, hidB, 512, 256, 256, 256);
  gemmT<2><<<dim3(1, 4), 512, 0, stream>>>(ow2T, hidB, ob2, out_latent, 512, 256, 128, 128);
  loss_kernel<<<dim3(1), 64, 0, stream>>>(accs, out_loss);
}